// Round 1
// baseline (1181.275 us; speedup 1.0000x reference)
//
#include <hip/hip_runtime.h>
#include <hip/hip_bf16.h>

// GNN_65498251264428: 2-layer GraphConv + mean pool + Linear(64,1).
// N=100000 nodes, E=1000000 edges, F=H=64, G=128 graphs.
//
// Key transform: layer 2 is linear, final output is w_lin . pooled + b_lin.
//   out[g] = (u.T_g + v.S_g)/c_g + (w_lin.b2_rel + b_lin)
//   u = w2_rel^T w_lin, v = w2_root^T w_lin
//   S_g = sum_{i in g} h1_i  -> per-node scalar q_i = v.h1_i
//   T_g = sum_{e: dst in g} w_e h1_{src_e} -> per-node scalar p_i = u.h1_i
// Only layer 1 (sparse aggr + dense 64x64 transform + relu) is done in full.

#define N_NODES 100000
#define N_EDGES 1000000
#define NGRAPHS 128

// ---- kernel 0: precompute u, v, and scalar constant C ----------------------
__global__ void prep_kernel(const float* __restrict__ w2rel,
                            const float* __restrict__ w2root,
                            const float* __restrict__ wlin,
                            const float* __restrict__ b2rel,
                            const float* __restrict__ blin,
                            float* __restrict__ u, float* __restrict__ v,
                            float* __restrict__ C) {
    int f = threadIdx.x;  // 64 threads
    float uu = 0.f, vv = 0.f;
    for (int h = 0; h < 64; ++h) {
        float wl = wlin[h];
        uu += wl * w2rel[h * 64 + f];
        vv += wl * w2root[h * 64 + f];
    }
    u[f] = uu;
    v[f] = vv;
    if (f == 0) {
        float c = blin[0];
        for (int h = 0; h < 64; ++h) c += wlin[h] * b2rel[h];
        *C = c;
    }
}

// ---- kernel 1: edge scatter  aggr[dst] += w_e * x[src]  --------------------
// 16 threads per edge, each does a float4 gather + 4 atomics.
__global__ __launch_bounds__(256) void scatter_kernel(
    const float* __restrict__ x, const int* __restrict__ ei,
    const float* __restrict__ ew, float* __restrict__ aggr, int E) {
    int idx = blockIdx.x * blockDim.x + threadIdx.x;  // E*16 threads
    int e = idx >> 4;
    int c = idx & 15;
    if (e >= E) return;
    int s = ei[e];
    int d = ei[E + e];
    float w = ew[e];
    float4 xv = ((const float4*)(x + (size_t)s * 64))[c];
    float* dp = aggr + (size_t)d * 64 + c * 4;
    atomicAdd(dp + 0, xv.x * w);
    atomicAdd(dp + 1, xv.y * w);
    atomicAdd(dp + 2, xv.z * w);
    atomicAdd(dp + 3, xv.w * w);
}

// ---- kernel 2: per-node h1 = relu(W1rel.aggr + b1 + W1root.x); p,q ---------
// One wave per node (grid-stride). Weights in LDS transposed: s[f*64+h] so
// lane-h reads at step f are consecutive (2 lanes/bank -> conflict-free).
__global__ __launch_bounds__(256) void node_kernel(
    const float* __restrict__ x, const float* __restrict__ aggr,
    const float* __restrict__ w1rel, const float* __restrict__ b1rel,
    const float* __restrict__ w1root, const float* __restrict__ u,
    const float* __restrict__ v, float* __restrict__ p, float* __restrict__ q,
    int N) {
    __shared__ float sRel[64 * 64];
    __shared__ float sRoot[64 * 64];
    __shared__ float sB[64], sU[64], sV[64];
    int tid = threadIdx.x;
    for (int i = tid; i < 4096; i += 256) {
        int h = i >> 6, f = i & 63;        // i = h*64+f in source layout
        sRel[f * 64 + h] = w1rel[i];
        sRoot[f * 64 + h] = w1root[i];
    }
    if (tid < 64) { sB[tid] = b1rel[tid]; sU[tid] = u[tid]; sV[tid] = v[tid]; }
    __syncthreads();

    int lane = tid & 63;
    int wave = tid >> 6;
    int gw = blockIdx.x * 4 + wave;
    int nw = gridDim.x * 4;
    for (int node = gw; node < N; node += nw) {
        float a = aggr[(size_t)node * 64 + lane];
        float xr = x[(size_t)node * 64 + lane];
        float acc = sB[lane];
#pragma unroll
        for (int f = 0; f < 64; ++f) {
            float af = __shfl(a, f);
            float xf = __shfl(xr, f);
            acc += sRel[f * 64 + lane] * af + sRoot[f * 64 + lane] * xf;
        }
        float h1 = fmaxf(acc, 0.f);
        float pc = sU[lane] * h1;
        float qc = sV[lane] * h1;
#pragma unroll
        for (int off = 32; off > 0; off >>= 1) {
            pc += __shfl_down(pc, off);
            qc += __shfl_down(qc, off);
        }
        if (lane == 0) { p[node] = pc; q[node] = qc; }
    }
}

// ---- kernel 3a: per-graph sum of q + counts --------------------------------
__global__ __launch_bounds__(256) void pool_nodes_kernel(
    const int* __restrict__ batch, const float* __restrict__ q,
    float* __restrict__ gq, float* __restrict__ gc, int N) {
    __shared__ float lq[NGRAPHS], lc[NGRAPHS];
    int tid = threadIdx.x;
    if (tid < NGRAPHS) { lq[tid] = 0.f; lc[tid] = 0.f; }
    __syncthreads();
    for (int i = blockIdx.x * blockDim.x + tid; i < N;
         i += gridDim.x * blockDim.x) {
        int g = batch[i];
        atomicAdd(&lq[g], q[i]);
        atomicAdd(&lc[g], 1.0f);
    }
    __syncthreads();
    if (tid < NGRAPHS) {
        atomicAdd(&gq[tid], lq[tid]);
        atomicAdd(&gc[tid], lc[tid]);
    }
}

// ---- kernel 3b: per-graph sum of w_e * p[src] over edges -------------------
__global__ __launch_bounds__(256) void pool_edges_kernel(
    const int* __restrict__ ei, const float* __restrict__ ew,
    const int* __restrict__ batch, const float* __restrict__ p,
    float* __restrict__ gp, int E) {
    __shared__ float lp[NGRAPHS];
    int tid = threadIdx.x;
    if (tid < NGRAPHS) lp[tid] = 0.f;
    __syncthreads();
    for (int e = blockIdx.x * blockDim.x + tid; e < E;
         e += gridDim.x * blockDim.x) {
        int s = ei[e];
        int d = ei[E + e];
        int g = batch[d];
        atomicAdd(&lp[g], ew[e] * p[s]);
    }
    __syncthreads();
    if (tid < NGRAPHS) atomicAdd(&gp[tid], lp[tid]);
}

// ---- kernel 4: epilogue ----------------------------------------------------
__global__ void final_kernel(const float* __restrict__ gp,
                             const float* __restrict__ gq,
                             const float* __restrict__ gc,
                             const float* __restrict__ C,
                             float* __restrict__ out) {
    int g = threadIdx.x;  // 128 threads
    float c = fmaxf(gc[g], 1.0f);
    out[g] = (gp[g] + gq[g]) / c + *C;
}

extern "C" void kernel_launch(void* const* d_in, const int* in_sizes, int n_in,
                              void* d_out, int out_size, void* d_ws,
                              size_t ws_size, hipStream_t stream) {
    const float* x      = (const float*)d_in[0];   // [N,64]
    const int*   ei     = (const int*)d_in[1];     // [2,E]
    const float* ew     = (const float*)d_in[2];   // [E]
    const int*   batch  = (const int*)d_in[3];     // [N]
    const float* w1rel  = (const float*)d_in[4];
    const float* b1rel  = (const float*)d_in[5];
    const float* w1root = (const float*)d_in[6];
    const float* w2rel  = (const float*)d_in[7];
    const float* b2rel  = (const float*)d_in[8];
    const float* w2root = (const float*)d_in[9];
    const float* wlin   = (const float*)d_in[10];
    const float* blin   = (const float*)d_in[11];
    float* out = (float*)d_out;

    // workspace layout (floats)
    float* aggr = (float*)d_ws;            // N*64 = 6,400,000
    float* p    = aggr + (size_t)N_NODES * 64;  // 100,000
    float* q    = p + N_NODES;             // 100,000
    float* u    = q + N_NODES;             // 64
    float* v    = u + 64;                  // 64
    float* gp   = v + 64;                  // 128
    float* gq   = gp + NGRAPHS;            // 128
    float* gc   = gq + NGRAPHS;            // 128
    float* C    = gc + NGRAPHS;            // 1

    // zero accumulators (ws is poisoned 0xAA before every call)
    hipMemsetAsync(aggr, 0, (size_t)N_NODES * 64 * sizeof(float), stream);
    hipMemsetAsync(gp, 0, (3 * NGRAPHS + 1) * sizeof(float), stream);

    prep_kernel<<<1, 64, 0, stream>>>(w2rel, w2root, wlin, b2rel, blin, u, v, C);

    int scatter_blocks = (N_EDGES * 16 + 255) / 256;
    scatter_kernel<<<scatter_blocks, 256, 0, stream>>>(x, ei, ew, aggr, N_EDGES);

    node_kernel<<<2048, 256, 0, stream>>>(x, aggr, w1rel, b1rel, w1root, u, v,
                                          p, q, N_NODES);

    pool_nodes_kernel<<<512, 256, 0, stream>>>(batch, q, gq, gc, N_NODES);
    pool_edges_kernel<<<1024, 256, 0, stream>>>(ei, ew, batch, p, gp, N_EDGES);

    final_kernel<<<1, NGRAPHS, 0, stream>>>(gp, gq, gc, C, out);
}

// Round 2
// 648.385 us; speedup vs baseline: 1.8219x; 1.8219x over previous
//
#include <hip/hip_runtime.h>
#include <hip/hip_bf16.h>

// GNN_65498251264428: 2-layer GraphConv + mean pool + Linear(64,1).
// N=100000 nodes, E=1000000 edges, F=H=64, G=128 graphs.
//
// Layer-2 algebraic collapse (layer 2 is linear):
//   out[g] = (u.T_g + v.S_g)/c_g + (w_lin.b2_rel + b_lin)
//   u = w2_rel^T w_lin, v = w2_root^T w_lin
//   S_g -> per-node scalar q_i = v.h1_i ; T_g -> per-edge w_e * p_{src}, p_i = u.h1_i
//
// Round 2: scatter-atomics (846us, 1GB coherent write traffic) replaced by
// runtime CSR build + gather. Node matmul holds W1 rows in VGPRs, broadcasts
// inputs via v_readlane (no LDS in hot loop). Pooling exploits sorted batch:
// per-wave contiguous node ranges, flush on graph change (~3 atomics/wave).

#define N_NODES 100000
#define N_EDGES 1000000
#define NGRAPHS 128

typedef float vf64 __attribute__((ext_vector_type(64)));

__device__ __forceinline__ float bcastf(float v, int l) {
    return __int_as_float(__builtin_amdgcn_readlane(__float_as_int(v), l));
}

// ---- kernel 0: precompute u, v, and scalar constant C ----------------------
__global__ void prep_kernel(const float* __restrict__ w2rel,
                            const float* __restrict__ w2root,
                            const float* __restrict__ wlin,
                            const float* __restrict__ b2rel,
                            const float* __restrict__ blin,
                            float* __restrict__ u, float* __restrict__ v,
                            float* __restrict__ C) {
    int f = threadIdx.x;  // 64 threads
    float uu = 0.f, vv = 0.f;
    for (int h = 0; h < 64; ++h) {
        float wl = wlin[h];
        uu += wl * w2rel[h * 64 + f];
        vv += wl * w2root[h * 64 + f];
    }
    u[f] = uu;
    v[f] = vv;
    if (f == 0) {
        float c = blin[0];
        for (int h = 0; h < 64; ++h) c += wlin[h] * b2rel[h];
        *C = c;
    }
}

// ---- kernel 1: histogram of in-degrees ------------------------------------
__global__ __launch_bounds__(256) void hist_kernel(const int* __restrict__ ei,
                                                   int* __restrict__ deg, int E) {
    int e = blockIdx.x * 256 + threadIdx.x;
    if (e < E) atomicAdd(&deg[ei[E + e]], 1);
}

// ---- kernel 2: exclusive scan -> row_ptr, cursor (single block) ------------
__global__ __launch_bounds__(1024) void scan_kernel(int* __restrict__ degcur,
                                                    int* __restrict__ row_ptr,
                                                    int N) {
    __shared__ int part[1024];
    int t = threadIdx.x;
    const int CH = (N + 1023) / 1024;
    int beg = t * CH, end = min(beg + CH, N);
    int s = 0;
    for (int i = beg; i < end; ++i) s += degcur[i];
    part[t] = s;
    __syncthreads();
    for (int off = 1; off < 1024; off <<= 1) {
        int vv = (t >= off) ? part[t - off] : 0;
        __syncthreads();
        part[t] += vv;
        __syncthreads();
    }
    int run = part[t] - s;  // exclusive prefix of this thread's chunk
    for (int i = beg; i < end; ++i) {
        int d = degcur[i];
        row_ptr[i] = run;
        degcur[i] = run;  // becomes the fill cursor
        run += d;
    }
    if (t == 1023) row_ptr[N] = part[1023];
}

// ---- kernel 3: fill CSR (src, weight) per dst ------------------------------
__global__ __launch_bounds__(256) void fill_kernel(
    const int* __restrict__ ei, const float* __restrict__ ew,
    int* __restrict__ cursor, int* __restrict__ csr_src,
    float* __restrict__ csr_w, int E) {
    int e = blockIdx.x * 256 + threadIdx.x;
    if (e >= E) return;
    int d = ei[E + e];
    int pos = atomicAdd(&cursor[d], 1);
    csr_src[pos] = ei[e];
    csr_w[pos] = ew[e];
}

// ---- kernel 4: fused gather + W1 matmul + relu + p store + q/count pool ----
// One wave per contiguous node range. W1 rows live in VGPRs (vf64 x2).
__global__ __launch_bounds__(256, 2) void gather_node_kernel(
    const float* __restrict__ x, const int* __restrict__ row_ptr,
    const int* __restrict__ csr_src, const float* __restrict__ csr_w,
    const float* __restrict__ w1rel, const float* __restrict__ b1rel,
    const float* __restrict__ w1root, const float* __restrict__ u,
    const float* __restrict__ v, const int* __restrict__ batch,
    float* __restrict__ p, float* __restrict__ gq, float* __restrict__ gc,
    int N, int chunk) {
    int lane = threadIdx.x & 63;
    int wid = (blockIdx.x * blockDim.x + threadIdx.x) >> 6;

    vf64 wrel, wroot;  // row `lane` of each weight matrix: 128 VGPRs
#pragma unroll
    for (int f = 0; f < 64; ++f) {
        wrel[f] = w1rel[lane * 64 + f];
        wroot[f] = w1root[lane * 64 + f];
    }
    float bb = b1rel[lane], uu = u[lane], vv = v[lane];

    int n0 = wid * chunk;
    int n1 = min(n0 + chunk, N);
    int curg = -1;
    float accq = 0.f, accc = 0.f;

    for (int node = n0; node < n1; ++node) {
        int beg = row_ptr[node], end = row_ptr[node + 1];
        float acc = 0.f;  // aggr[node][lane]
        for (int j0 = beg; j0 < end; j0 += 64) {
            int jj = j0 + lane;
            int s = 0;
            float w = 0.f;
            if (jj < end) { s = csr_src[jj]; w = csr_w[jj]; }
            int cnt = min(64, end - j0);
            int k = 0;
            for (; k + 3 < cnt; k += 4) {
                int s0 = __shfl(s, k), s1 = __shfl(s, k + 1);
                int s2 = __shfl(s, k + 2), s3 = __shfl(s, k + 3);
                float w0 = __shfl(w, k), w1 = __shfl(w, k + 1);
                float w2 = __shfl(w, k + 2), w3 = __shfl(w, k + 3);
                float x0 = x[(size_t)s0 * 64 + lane];
                float x1 = x[(size_t)s1 * 64 + lane];
                float x2 = x[(size_t)s2 * 64 + lane];
                float x3 = x[(size_t)s3 * 64 + lane];
                acc += w0 * x0;
                acc += w1 * x1;
                acc += w2 * x2;
                acc += w3 * x3;
            }
            for (; k < cnt; ++k) {
                int sk = __shfl(s, k);
                float wk = __shfl(w, k);
                acc += wk * x[(size_t)sk * 64 + lane];
            }
        }
        float xr = x[(size_t)node * 64 + lane];
        float t = bb;
#pragma unroll
        for (int f = 0; f < 64; ++f) {
            t += wrel[f] * bcastf(acc, f);
            t += wroot[f] * bcastf(xr, f);
        }
        float h1 = fmaxf(t, 0.f);
        float pc = uu * h1, qc = vv * h1;
#pragma unroll
        for (int off = 32; off; off >>= 1) {
            pc += __shfl_xor(pc, off);
            qc += __shfl_xor(qc, off);
        }
        if (lane == 0) p[node] = pc;
        int g = batch[node];
        if (g != curg) {
            if (curg >= 0 && lane == 0) {
                atomicAdd(&gq[curg], accq);
                atomicAdd(&gc[curg], accc);
            }
            curg = g;
            accq = 0.f;
            accc = 0.f;
        }
        accq += qc;
        accc += 1.f;
    }
    if (curg >= 0 && lane == 0) {
        atomicAdd(&gq[curg], accq);
        atomicAdd(&gc[curg], accc);
    }
}

// ---- kernel 5: T_g = sum over edges of w_e * p[src], grouped by dst graph --
__global__ __launch_bounds__(256) void pool_t_kernel(
    const int* __restrict__ row_ptr, const int* __restrict__ csr_src,
    const float* __restrict__ csr_w, const float* __restrict__ p,
    const int* __restrict__ batch, float* __restrict__ gp, int N, int chunk) {
    int lane = threadIdx.x & 63;
    int wid = (blockIdx.x * blockDim.x + threadIdx.x) >> 6;
    int n0 = wid * chunk;
    int n1 = min(n0 + chunk, N);
    int curg = -1;
    float acct = 0.f;  // per-lane partial; reduced only at flush
    for (int node = n0; node < n1; ++node) {
        int g = batch[node];
        if (g != curg) {
            if (curg >= 0) {
                float t = acct;
#pragma unroll
                for (int off = 32; off; off >>= 1) t += __shfl_xor(t, off);
                if (lane == 0) atomicAdd(&gp[curg], t);
            }
            curg = g;
            acct = 0.f;
        }
        int beg = row_ptr[node], end = row_ptr[node + 1];
        for (int jj = beg + lane; jj < end; jj += 64)
            acct += csr_w[jj] * p[csr_src[jj]];
    }
    if (curg >= 0) {
        float t = acct;
#pragma unroll
        for (int off = 32; off; off >>= 1) t += __shfl_xor(t, off);
        if (lane == 0) atomicAdd(&gp[curg], t);
    }
}

// ---- kernel 6: epilogue ----------------------------------------------------
__global__ void final_kernel(const float* __restrict__ gp,
                             const float* __restrict__ gq,
                             const float* __restrict__ gc,
                             const float* __restrict__ C,
                             float* __restrict__ out) {
    int g = threadIdx.x;  // 128 threads
    float c = fmaxf(gc[g], 1.0f);
    out[g] = (gp[g] + gq[g]) / c + *C;
}

extern "C" void kernel_launch(void* const* d_in, const int* in_sizes, int n_in,
                              void* d_out, int out_size, void* d_ws,
                              size_t ws_size, hipStream_t stream) {
    const float* x      = (const float*)d_in[0];   // [N,64]
    const int*   ei     = (const int*)d_in[1];     // [2,E]
    const float* ew     = (const float*)d_in[2];   // [E]
    const int*   batch  = (const int*)d_in[3];     // [N] sorted
    const float* w1rel  = (const float*)d_in[4];
    const float* b1rel  = (const float*)d_in[5];
    const float* w1root = (const float*)d_in[6];
    const float* w2rel  = (const float*)d_in[7];
    const float* b2rel  = (const float*)d_in[8];
    const float* w2root = (const float*)d_in[9];
    const float* wlin   = (const float*)d_in[10];
    const float* blin   = (const float*)d_in[11];
    float* out = (float*)d_out;

    // workspace layout
    int*   row_ptr = (int*)d_ws;                      // N+1
    int*   cursor  = row_ptr + (N_NODES + 1);         // N (deg -> cursor)
    int*   csr_src = cursor + N_NODES;                // E
    float* csr_w   = (float*)(csr_src + N_EDGES);     // E
    float* p       = csr_w + N_EDGES;                 // N
    float* u       = p + N_NODES;                     // 64
    float* v       = u + 64;                          // 64
    float* gp      = v + 64;                          // 128
    float* gq      = gp + NGRAPHS;                    // 128
    float* gc      = gq + NGRAPHS;                    // 128
    float* C       = gc + NGRAPHS;                    // 1

    hipMemsetAsync(cursor, 0, N_NODES * sizeof(int), stream);
    hipMemsetAsync(gp, 0, (3 * NGRAPHS + 1) * sizeof(float), stream);

    prep_kernel<<<1, 64, 0, stream>>>(w2rel, w2root, wlin, b2rel, blin, u, v, C);

    int eblocks = (N_EDGES + 255) / 256;
    hist_kernel<<<eblocks, 256, 0, stream>>>(ei, cursor, N_EDGES);
    scan_kernel<<<1, 1024, 0, stream>>>(cursor, row_ptr, N_NODES);
    fill_kernel<<<eblocks, 256, 0, stream>>>(ei, ew, cursor, csr_src, csr_w,
                                             N_EDGES);

    {
        int blocks = 1024;                       // 4096 waves
        int waves = blocks * (256 / 64);
        int chunk = (N_NODES + waves - 1) / waves;  // 25 nodes/wave
        gather_node_kernel<<<blocks, 256, 0, stream>>>(
            x, row_ptr, csr_src, csr_w, w1rel, b1rel, w1root, u, v, batch, p,
            gq, gc, N_NODES, chunk);
    }
    {
        int blocks = 512;                        // 2048 waves
        int waves = blocks * (256 / 64);
        int chunk = (N_NODES + waves - 1) / waves;  // 49 nodes/wave
        pool_t_kernel<<<blocks, 256, 0, stream>>>(row_ptr, csr_src, csr_w, p,
                                                  batch, gp, N_NODES, chunk);
    }
    final_kernel<<<1, NGRAPHS, 0, stream>>>(gp, gq, gc, C, out);
}

// Round 3
// 430.995 us; speedup vs baseline: 2.7408x; 1.5044x over previous
//
#include <hip/hip_runtime.h>
#include <hip/hip_bf16.h>

// GNN_65498251264428: 2-layer GraphConv + mean pool + Linear(64,1).
// N=100000 nodes, E=1000000 edges, F=H=64, G=128 graphs.
//
// Layer-2 algebraic collapse (layer 2 is linear):
//   out[g] = (u.T_g + v.S_g)/c_g + (w_lin.b2_rel + b_lin)
//   u = w2_rel^T w_lin, v = w2_root^T w_lin
//   S_g -> per-node scalar q_i = v.h1_i ; T_g -> per-edge w_e * p_{src}, p_i = u.h1_i
//
// Round 3: single-block scan (232us, one CU, latency-bound) replaced by
// 3-phase multi-block scan (blocksum -> scan partials -> local scan+offset).

#define N_NODES 100000
#define N_EDGES 1000000
#define NGRAPHS 128
#define SCAN_NB ((N_NODES + 1023) / 1024)   // 98 blocks

typedef float vf64 __attribute__((ext_vector_type(64)));

__device__ __forceinline__ float bcastf(float v, int l) {
    return __int_as_float(__builtin_amdgcn_readlane(__float_as_int(v), l));
}

// ---- kernel 0: precompute u, v, and scalar constant C ----------------------
__global__ void prep_kernel(const float* __restrict__ w2rel,
                            const float* __restrict__ w2root,
                            const float* __restrict__ wlin,
                            const float* __restrict__ b2rel,
                            const float* __restrict__ blin,
                            float* __restrict__ u, float* __restrict__ v,
                            float* __restrict__ C) {
    int f = threadIdx.x;  // 64 threads
    float uu = 0.f, vv = 0.f;
    for (int h = 0; h < 64; ++h) {
        float wl = wlin[h];
        uu += wl * w2rel[h * 64 + f];
        vv += wl * w2root[h * 64 + f];
    }
    u[f] = uu;
    v[f] = vv;
    if (f == 0) {
        float c = blin[0];
        for (int h = 0; h < 64; ++h) c += wlin[h] * b2rel[h];
        *C = c;
    }
}

// ---- kernel 1: histogram of in-degrees ------------------------------------
__global__ __launch_bounds__(256) void hist_kernel(const int* __restrict__ ei,
                                                   int* __restrict__ deg, int E) {
    int e = blockIdx.x * 256 + threadIdx.x;
    if (e < E) atomicAdd(&deg[ei[E + e]], 1);
}

// ---- scan phase A: per-block sums ------------------------------------------
__global__ __launch_bounds__(1024) void scan_phaseA(const int* __restrict__ deg,
                                                    int* __restrict__ blocksum,
                                                    int N) {
    int gid = blockIdx.x * 1024 + threadIdx.x;
    int v = (gid < N) ? deg[gid] : 0;
    int lane = threadIdx.x & 63;
    int wv = threadIdx.x >> 6;
#pragma unroll
    for (int off = 32; off; off >>= 1) v += __shfl_xor(v, off);
    __shared__ int ws[16];
    if (lane == 0) ws[wv] = v;
    __syncthreads();
    if (threadIdx.x < 16) {
        int s = ws[threadIdx.x];
#pragma unroll
        for (int off = 8; off; off >>= 1) s += __shfl_xor(s, off, 16);
        if (threadIdx.x == 0) blocksum[blockIdx.x] = s;
    }
}

// ---- scan phase B: exclusive scan of block sums (NB <= 128) ----------------
__global__ void scan_phaseB(int* __restrict__ blocksum, int NB) {
    __shared__ int s[128];
    int t = threadIdx.x;  // 128 threads
    int v = (t < NB) ? blocksum[t] : 0;
    s[t] = v;
    __syncthreads();
    for (int off = 1; off < 128; off <<= 1) {
        int x = (t >= off) ? s[t - off] : 0;
        __syncthreads();
        s[t] += x;
        __syncthreads();
    }
    if (t < NB) blocksum[t] = s[t] - v;  // exclusive
}

// ---- scan phase C: local exclusive scan + block offset ---------------------
__global__ __launch_bounds__(1024) void scan_phaseC(
    const int* __restrict__ deg, const int* __restrict__ blocksum,
    int* __restrict__ row_ptr, int* __restrict__ cursor, int N) {
    int gid = blockIdx.x * 1024 + threadIdx.x;
    int v = (gid < N) ? deg[gid] : 0;
    int lane = threadIdx.x & 63;
    int wv = threadIdx.x >> 6;
    int sc = v;  // inclusive scan within wave
#pragma unroll
    for (int off = 1; off < 64; off <<= 1) {
        int x = __shfl_up(sc, off);
        if (lane >= off) sc += x;
    }
    __shared__ int ws[16];
    if (lane == 63) ws[wv] = sc;
    __syncthreads();
    if (threadIdx.x < 16) {
        int wsv = ws[threadIdx.x];
        int scw = wsv;
#pragma unroll
        for (int off = 1; off < 16; off <<= 1) {
            int x = __shfl_up(scw, off, 16);
            if (threadIdx.x >= off) scw += x;
        }
        ws[threadIdx.x] = scw - wsv;  // exclusive wave offset
    }
    __syncthreads();
    int excl = (sc - v) + ws[wv] + blocksum[blockIdx.x];
    if (gid < N) {
        row_ptr[gid] = excl;
        cursor[gid] = excl;
    }
    if (gid == N - 1) row_ptr[N] = excl + v;  // == E
}

// ---- kernel 3: fill CSR (src, weight) per dst ------------------------------
__global__ __launch_bounds__(256) void fill_kernel(
    const int* __restrict__ ei, const float* __restrict__ ew,
    int* __restrict__ cursor, int* __restrict__ csr_src,
    float* __restrict__ csr_w, int E) {
    int e = blockIdx.x * 256 + threadIdx.x;
    if (e >= E) return;
    int d = ei[E + e];
    int pos = atomicAdd(&cursor[d], 1);
    csr_src[pos] = ei[e];
    csr_w[pos] = ew[e];
}

// ---- kernel 4: fused gather + W1 matmul + relu + p store + q/count pool ----
// One wave per contiguous node range. W1 rows live in VGPRs (vf64 x2).
__global__ __launch_bounds__(256, 2) void gather_node_kernel(
    const float* __restrict__ x, const int* __restrict__ row_ptr,
    const int* __restrict__ csr_src, const float* __restrict__ csr_w,
    const float* __restrict__ w1rel, const float* __restrict__ b1rel,
    const float* __restrict__ w1root, const float* __restrict__ u,
    const float* __restrict__ v, const int* __restrict__ batch,
    float* __restrict__ p, float* __restrict__ gq, float* __restrict__ gc,
    int N, int chunk) {
    int lane = threadIdx.x & 63;
    int wid = (blockIdx.x * blockDim.x + threadIdx.x) >> 6;

    vf64 wrel, wroot;  // row `lane` of each weight matrix: 128 VGPRs
#pragma unroll
    for (int f = 0; f < 64; ++f) {
        wrel[f] = w1rel[lane * 64 + f];
        wroot[f] = w1root[lane * 64 + f];
    }
    float bb = b1rel[lane], uu = u[lane], vv = v[lane];

    int n0 = wid * chunk;
    int n1 = min(n0 + chunk, N);
    int curg = -1;
    float accq = 0.f, accc = 0.f;

    for (int node = n0; node < n1; ++node) {
        int beg = row_ptr[node], end = row_ptr[node + 1];
        float acc = 0.f;  // aggr[node][lane]
        for (int j0 = beg; j0 < end; j0 += 64) {
            int jj = j0 + lane;
            int s = 0;
            float w = 0.f;
            if (jj < end) { s = csr_src[jj]; w = csr_w[jj]; }
            int cnt = min(64, end - j0);
            int k = 0;
            for (; k + 3 < cnt; k += 4) {
                int s0 = __shfl(s, k), s1 = __shfl(s, k + 1);
                int s2 = __shfl(s, k + 2), s3 = __shfl(s, k + 3);
                float w0 = __shfl(w, k), w1 = __shfl(w, k + 1);
                float w2 = __shfl(w, k + 2), w3 = __shfl(w, k + 3);
                float x0 = x[(size_t)s0 * 64 + lane];
                float x1 = x[(size_t)s1 * 64 + lane];
                float x2 = x[(size_t)s2 * 64 + lane];
                float x3 = x[(size_t)s3 * 64 + lane];
                acc += w0 * x0;
                acc += w1 * x1;
                acc += w2 * x2;
                acc += w3 * x3;
            }
            for (; k < cnt; ++k) {
                int sk = __shfl(s, k);
                float wk = __shfl(w, k);
                acc += wk * x[(size_t)sk * 64 + lane];
            }
        }
        float xr = x[(size_t)node * 64 + lane];
        float t = bb;
#pragma unroll
        for (int f = 0; f < 64; ++f) {
            t += wrel[f] * bcastf(acc, f);
            t += wroot[f] * bcastf(xr, f);
        }
        float h1 = fmaxf(t, 0.f);
        float pc = uu * h1, qc = vv * h1;
#pragma unroll
        for (int off = 32; off; off >>= 1) {
            pc += __shfl_xor(pc, off);
            qc += __shfl_xor(qc, off);
        }
        if (lane == 0) p[node] = pc;
        int g = batch[node];
        if (g != curg) {
            if (curg >= 0 && lane == 0) {
                atomicAdd(&gq[curg], accq);
                atomicAdd(&gc[curg], accc);
            }
            curg = g;
            accq = 0.f;
            accc = 0.f;
        }
        accq += qc;
        accc += 1.f;
    }
    if (curg >= 0 && lane == 0) {
        atomicAdd(&gq[curg], accq);
        atomicAdd(&gc[curg], accc);
    }
}

// ---- kernel 5: T_g = sum over edges of w_e * p[src], grouped by dst graph --
__global__ __launch_bounds__(256) void pool_t_kernel(
    const int* __restrict__ row_ptr, const int* __restrict__ csr_src,
    const float* __restrict__ csr_w, const float* __restrict__ p,
    const int* __restrict__ batch, float* __restrict__ gp, int N, int chunk) {
    int lane = threadIdx.x & 63;
    int wid = (blockIdx.x * blockDim.x + threadIdx.x) >> 6;
    int n0 = wid * chunk;
    int n1 = min(n0 + chunk, N);
    int curg = -1;
    float acct = 0.f;  // per-lane partial; reduced only at flush
    for (int node = n0; node < n1; ++node) {
        int g = batch[node];
        if (g != curg) {
            if (curg >= 0) {
                float t = acct;
#pragma unroll
                for (int off = 32; off; off >>= 1) t += __shfl_xor(t, off);
                if (lane == 0) atomicAdd(&gp[curg], t);
            }
            curg = g;
            acct = 0.f;
        }
        int beg = row_ptr[node], end = row_ptr[node + 1];
        for (int jj = beg + lane; jj < end; jj += 64)
            acct += csr_w[jj] * p[csr_src[jj]];
    }
    if (curg >= 0) {
        float t = acct;
#pragma unroll
        for (int off = 32; off; off >>= 1) t += __shfl_xor(t, off);
        if (lane == 0) atomicAdd(&gp[curg], t);
    }
}

// ---- kernel 6: epilogue ----------------------------------------------------
__global__ void final_kernel(const float* __restrict__ gp,
                             const float* __restrict__ gq,
                             const float* __restrict__ gc,
                             const float* __restrict__ C,
                             float* __restrict__ out) {
    int g = threadIdx.x;  // 128 threads
    float c = fmaxf(gc[g], 1.0f);
    out[g] = (gp[g] + gq[g]) / c + *C;
}

extern "C" void kernel_launch(void* const* d_in, const int* in_sizes, int n_in,
                              void* d_out, int out_size, void* d_ws,
                              size_t ws_size, hipStream_t stream) {
    const float* x      = (const float*)d_in[0];   // [N,64]
    const int*   ei     = (const int*)d_in[1];     // [2,E]
    const float* ew     = (const float*)d_in[2];   // [E]
    const int*   batch  = (const int*)d_in[3];     // [N] sorted
    const float* w1rel  = (const float*)d_in[4];
    const float* b1rel  = (const float*)d_in[5];
    const float* w1root = (const float*)d_in[6];
    const float* w2rel  = (const float*)d_in[7];
    const float* b2rel  = (const float*)d_in[8];
    const float* w2root = (const float*)d_in[9];
    const float* wlin   = (const float*)d_in[10];
    const float* blin   = (const float*)d_in[11];
    float* out = (float*)d_out;

    // workspace layout
    int*   deg      = (int*)d_ws;                     // N
    int*   row_ptr  = deg + N_NODES;                  // N+1
    int*   cursor   = row_ptr + (N_NODES + 1);        // N
    int*   blocksum = cursor + N_NODES;               // 128 (pad)
    int*   csr_src  = blocksum + 128;                 // E
    float* csr_w    = (float*)(csr_src + N_EDGES);    // E
    float* p        = csr_w + N_EDGES;                // N
    float* u        = p + N_NODES;                    // 64
    float* v        = u + 64;                         // 64
    float* gp       = v + 64;                         // 128
    float* gq       = gp + NGRAPHS;                   // 128
    float* gc       = gq + NGRAPHS;                   // 128
    float* C        = gc + NGRAPHS;                   // 1

    hipMemsetAsync(deg, 0, N_NODES * sizeof(int), stream);
    hipMemsetAsync(gp, 0, (3 * NGRAPHS + 1) * sizeof(float), stream);

    prep_kernel<<<1, 64, 0, stream>>>(w2rel, w2root, wlin, b2rel, blin, u, v, C);

    int eblocks = (N_EDGES + 255) / 256;
    hist_kernel<<<eblocks, 256, 0, stream>>>(ei, deg, N_EDGES);

    scan_phaseA<<<SCAN_NB, 1024, 0, stream>>>(deg, blocksum, N_NODES);
    scan_phaseB<<<1, 128, 0, stream>>>(blocksum, SCAN_NB);
    scan_phaseC<<<SCAN_NB, 1024, 0, stream>>>(deg, blocksum, row_ptr, cursor,
                                              N_NODES);

    fill_kernel<<<eblocks, 256, 0, stream>>>(ei, ew, cursor, csr_src, csr_w,
                                             N_EDGES);

    {
        int blocks = 1024;                          // 4096 waves
        int waves = blocks * (256 / 64);
        int chunk = (N_NODES + waves - 1) / waves;  // 25 nodes/wave
        gather_node_kernel<<<blocks, 256, 0, stream>>>(
            x, row_ptr, csr_src, csr_w, w1rel, b1rel, w1root, u, v, batch, p,
            gq, gc, N_NODES, chunk);
    }
    {
        int blocks = 512;                           // 2048 waves
        int waves = blocks * (256 / 64);
        int chunk = (N_NODES + waves - 1) / waves;  // 49 nodes/wave
        pool_t_kernel<<<blocks, 256, 0, stream>>>(row_ptr, csr_src, csr_w, p,
                                                  batch, gp, N_NODES, chunk);
    }
    final_kernel<<<1, NGRAPHS, 0, stream>>>(gp, gq, gc, C, out);
}

// Round 4
// 346.099 us; speedup vs baseline: 3.4131x; 1.2453x over previous
//
#include <hip/hip_runtime.h>
#include <hip/hip_bf16.h>

// GNN_65498251264428: 2-layer GraphConv + mean pool + Linear(64,1).
// N=100000 nodes, E=1000000 edges, F=H=64, G=128 graphs.
//
// Layer-2 algebraic collapse (layer 2 is linear):
//   out[g] = (u.T_g + v.S_g)/c_g + (w_lin.b2_rel + b_lin)
//   u = w2_rel^T w_lin, v = w2_root^T w_lin
//   S_g -> per-node scalar q_i = v.h1_i ; T_g -> per-edge w_e * p_{src}
//
// Round 4: split gather (sparse, 16-lane/edge float4, bf16 aggr out) from
// dense transform (MFMA 16x16x32 bf16; A=inputs single bf16, B=weights
// hi/lo-split so weight rounding error vanishes). CSR packed int2.

#define N_NODES 100000
#define N_EDGES 1000000
#define NGRAPHS 128
#define SCAN_NB ((N_NODES + 1023) / 1024)  // 98 blocks

typedef __attribute__((ext_vector_type(8))) short bf16x8;
typedef __attribute__((ext_vector_type(4))) float f32x4;

__device__ __forceinline__ unsigned short f2bf(float f) {
    unsigned u = __float_as_uint(f);
    unsigned r = (u + 0x7FFFu + ((u >> 16) & 1u)) >> 16;  // RNE
    return (unsigned short)r;
}
__device__ __forceinline__ float bf2f(unsigned short h) {
    return __uint_as_float(((unsigned)h) << 16);
}

// ---- kernel 0: u, v, C + hi/lo bf16 split of W1rel/W1root ------------------
__global__ __launch_bounds__(256) void prep_kernel(
    const float* __restrict__ w1rel, const float* __restrict__ w1root,
    const float* __restrict__ w2rel, const float* __restrict__ w2root,
    const float* __restrict__ wlin, const float* __restrict__ b2rel,
    const float* __restrict__ blin, unsigned short* __restrict__ whirel,
    unsigned short* __restrict__ wlorel, unsigned short* __restrict__ whiroot,
    unsigned short* __restrict__ wloroot, float* __restrict__ u,
    float* __restrict__ v, float* __restrict__ C) {
    int tid = threadIdx.x;
    for (int i = tid; i < 4096; i += 256) {
        float a = w1rel[i];
        unsigned short hi = f2bf(a);
        whirel[i] = hi;
        wlorel[i] = f2bf(a - bf2f(hi));
        float b = w1root[i];
        unsigned short hb = f2bf(b);
        whiroot[i] = hb;
        wloroot[i] = f2bf(b - bf2f(hb));
    }
    if (tid < 64) {
        float uu = 0.f, vv = 0.f;
        for (int h = 0; h < 64; ++h) {
            float wl = wlin[h];
            uu += wl * w2rel[h * 64 + tid];
            vv += wl * w2root[h * 64 + tid];
        }
        u[tid] = uu;
        v[tid] = vv;
    }
    if (tid == 0) {
        float c = blin[0];
        for (int h = 0; h < 64; ++h) c += wlin[h] * b2rel[h];
        *C = c;
    }
}

// ---- kernel 1: histogram of in-degrees -------------------------------------
__global__ __launch_bounds__(256) void hist_kernel(const int* __restrict__ ei,
                                                   int* __restrict__ deg, int E) {
    int e = blockIdx.x * 256 + threadIdx.x;
    if (e < E) atomicAdd(&deg[ei[E + e]], 1);
}

// ---- scan phase A: per-block sums ------------------------------------------
__global__ __launch_bounds__(1024) void scan_phaseA(const int* __restrict__ deg,
                                                    int* __restrict__ blocksum,
                                                    int N) {
    int gid = blockIdx.x * 1024 + threadIdx.x;
    int v = (gid < N) ? deg[gid] : 0;
    int lane = threadIdx.x & 63;
    int wv = threadIdx.x >> 6;
#pragma unroll
    for (int off = 32; off; off >>= 1) v += __shfl_xor(v, off);
    __shared__ int ws[16];
    if (lane == 0) ws[wv] = v;
    __syncthreads();
    if (threadIdx.x < 16) {
        int s = ws[threadIdx.x];
#pragma unroll
        for (int off = 8; off; off >>= 1) s += __shfl_xor(s, off, 16);
        if (threadIdx.x == 0) blocksum[blockIdx.x] = s;
    }
}

// ---- scan phase B: exclusive scan of block sums ----------------------------
__global__ void scan_phaseB(int* __restrict__ blocksum, int NB) {
    __shared__ int s[128];
    int t = threadIdx.x;  // 128 threads
    int v = (t < NB) ? blocksum[t] : 0;
    s[t] = v;
    __syncthreads();
    for (int off = 1; off < 128; off <<= 1) {
        int x = (t >= off) ? s[t - off] : 0;
        __syncthreads();
        s[t] += x;
        __syncthreads();
    }
    if (t < NB) blocksum[t] = s[t] - v;  // exclusive
}

// ---- scan phase C: local exclusive scan + block offset ---------------------
__global__ __launch_bounds__(1024) void scan_phaseC(
    const int* __restrict__ deg, const int* __restrict__ blocksum,
    int* __restrict__ row_ptr, int* __restrict__ cursor, int N) {
    int gid = blockIdx.x * 1024 + threadIdx.x;
    int v = (gid < N) ? deg[gid] : 0;
    int lane = threadIdx.x & 63;
    int wv = threadIdx.x >> 6;
    int sc = v;
#pragma unroll
    for (int off = 1; off < 64; off <<= 1) {
        int x = __shfl_up(sc, off);
        if (lane >= off) sc += x;
    }
    __shared__ int ws[16];
    if (lane == 63) ws[wv] = sc;
    __syncthreads();
    if (threadIdx.x < 16) {
        int wsv = ws[threadIdx.x];
        int scw = wsv;
#pragma unroll
        for (int off = 1; off < 16; off <<= 1) {
            int x = __shfl_up(scw, off, 16);
            if (threadIdx.x >= off) scw += x;
        }
        ws[threadIdx.x] = scw - wsv;
    }
    __syncthreads();
    int excl = (sc - v) + ws[wv] + blocksum[blockIdx.x];
    if (gid < N) {
        row_ptr[gid] = excl;
        cursor[gid] = excl;
    }
    if (gid == N - 1) row_ptr[N] = excl + v;  // == E
}

// ---- kernel 3: fill CSR packed (src, w) per dst ----------------------------
__global__ __launch_bounds__(256) void fill_kernel(
    const int* __restrict__ ei, const float* __restrict__ ew,
    int* __restrict__ cursor, int2* __restrict__ csr, int E) {
    int e = blockIdx.x * 256 + threadIdx.x;
    if (e >= E) return;
    int d = ei[E + e];
    int2 val;
    val.x = ei[e];
    val.y = __float_as_int(ew[e]);
    int pos = atomicAdd(&cursor[d], 1);
    csr[pos] = val;
}

// ---- kernel 4: gather  aggr[n] = sum_e w_e x[src_e]  (bf16 out) ------------
// 16 lanes per edge x 4 edges in parallel; float4 gathers; xor-reduce groups.
__global__ __launch_bounds__(256) void gather_kernel(
    const float* __restrict__ x, const int* __restrict__ row_ptr,
    const int2* __restrict__ csr, unsigned short* __restrict__ aggr, int N,
    int chunk) {
    int lane = threadIdx.x & 63;
    int wid = (blockIdx.x * blockDim.x + threadIdx.x) >> 6;
    int g = lane >> 4;   // edge slot within group of 4
    int c = lane & 15;   // float4 chunk of the 64-wide row
    int n0 = wid * chunk;
    int n1 = min(n0 + chunk, N);
    for (int node = n0; node < n1; ++node) {
        int beg = row_ptr[node], end = row_ptr[node + 1];
        float4 acc = {0.f, 0.f, 0.f, 0.f};
        for (int j0 = beg; j0 < end; j0 += 64) {
            int cnt = min(64, end - j0);
            int2 e = {0, 0};
            if (lane < cnt) e = csr[j0 + lane];
            for (int k = 0; k < cnt; k += 4) {
                int myk = k + g;
                int sj = __shfl(e.x, myk);
                float wj = __int_as_float(__shfl(e.y, myk));
                if (myk < cnt) {
                    float4 xv = *(const float4*)(x + (size_t)sj * 64 + c * 4);
                    acc.x += wj * xv.x;
                    acc.y += wj * xv.y;
                    acc.z += wj * xv.z;
                    acc.w += wj * xv.w;
                }
            }
        }
#pragma unroll
        for (int off = 16; off < 64; off <<= 1) {
            acc.x += __shfl_xor(acc.x, off);
            acc.y += __shfl_xor(acc.y, off);
            acc.z += __shfl_xor(acc.z, off);
            acc.w += __shfl_xor(acc.w, off);
        }
        if (lane < 16) {
            ushort4 o;
            o.x = f2bf(acc.x);
            o.y = f2bf(acc.y);
            o.z = f2bf(acc.z);
            o.w = f2bf(acc.w);
            *(ushort4*)(aggr + (size_t)node * 64 + c * 4) = o;
        }
    }
}

// ---- kernel 5: dense MFMA  t = aggr.Wrel^T + x.Wroot^T + b; p,q ------------
// One wave per 16-node tile. A: m=lane&15, k=quad*8+j. D: col=lane&15 (=h),
// row=quad*4+reg (=node). Weights hi/lo split: A.(Whi+Wlo).
__global__ __launch_bounds__(256, 2) void dense_kernel(
    const unsigned short* __restrict__ aggr, const float* __restrict__ x,
    const unsigned short* __restrict__ whirel,
    const unsigned short* __restrict__ wlorel,
    const unsigned short* __restrict__ whiroot,
    const unsigned short* __restrict__ wloroot,
    const float* __restrict__ b1rel, const float* __restrict__ u,
    const float* __restrict__ v, float* __restrict__ p, float* __restrict__ q,
    int N) {
    int lane = threadIdx.x & 63;
    int wave = (blockIdx.x << 2) + (threadIdx.x >> 6);
    int nb = wave * 16;
    if (nb >= N) return;
    int lo4 = lane & 15;
    int quad = lane >> 4;

    f32x4 acc[4];
#pragma unroll
    for (int t = 0; t < 4; ++t) acc[t] = (f32x4){0.f, 0.f, 0.f, 0.f};

    for (int s = 0; s < 2; ++s) {  // K-step: f in [s*32, s*32+32)
        // A-fragments
        bf16x8 Aa = *(const bf16x8*)(aggr + (size_t)(nb + lo4) * 64 + s * 32 +
                                     quad * 8);
        const float* xp = x + (size_t)(nb + lo4) * 64 + s * 32 + quad * 8;
        bf16x8 Ax;
#pragma unroll
        for (int j = 0; j < 8; ++j) Ax[j] = (short)f2bf(xp[j]);
#pragma unroll
        for (int t = 0; t < 4; ++t) {  // h-tile: h in [t*16, t*16+16)
            int off = (t * 16 + lo4) * 64 + s * 32 + quad * 8;
            bf16x8 bhr = *(const bf16x8*)(whirel + off);
            bf16x8 blr = *(const bf16x8*)(wlorel + off);
            bf16x8 bhx = *(const bf16x8*)(whiroot + off);
            bf16x8 blx = *(const bf16x8*)(wloroot + off);
            acc[t] = __builtin_amdgcn_mfma_f32_16x16x32_bf16(Aa, bhr, acc[t],
                                                             0, 0, 0);
            acc[t] = __builtin_amdgcn_mfma_f32_16x16x32_bf16(Aa, blr, acc[t],
                                                             0, 0, 0);
            acc[t] = __builtin_amdgcn_mfma_f32_16x16x32_bf16(Ax, bhx, acc[t],
                                                             0, 0, 0);
            acc[t] = __builtin_amdgcn_mfma_f32_16x16x32_bf16(Ax, blx, acc[t],
                                                             0, 0, 0);
        }
    }

    float pc[4] = {0.f, 0.f, 0.f, 0.f};
    float qc[4] = {0.f, 0.f, 0.f, 0.f};
#pragma unroll
    for (int t = 0; t < 4; ++t) {
        float bb = b1rel[t * 16 + lo4];
        float uu = u[t * 16 + lo4];
        float vv = v[t * 16 + lo4];
#pragma unroll
        for (int r = 0; r < 4; ++r) {
            float h1 = fmaxf(acc[t][r] + bb, 0.f);
            pc[r] += uu * h1;
            qc[r] += vv * h1;
        }
    }
#pragma unroll
    for (int off = 1; off < 16; off <<= 1) {
#pragma unroll
        for (int r = 0; r < 4; ++r) {
            pc[r] += __shfl_xor(pc[r], off);
            qc[r] += __shfl_xor(qc[r], off);
        }
    }
    if (lo4 == 0) {  // lanes 0,16,32,48: nodes nb+quad*4 .. +3
        f32x4 po = {pc[0], pc[1], pc[2], pc[3]};
        f32x4 qo = {qc[0], qc[1], qc[2], qc[3]};
        *(f32x4*)(p + nb + quad * 4) = po;
        *(f32x4*)(q + nb + quad * 4) = qo;
    }
}

// ---- kernel 6: pooled reductions (T_g via CSR, S_g via q, counts) ----------
__global__ __launch_bounds__(256) void pool_kernel(
    const int* __restrict__ row_ptr, const int2* __restrict__ csr,
    const float* __restrict__ p, const float* __restrict__ q,
    const int* __restrict__ batch, float* __restrict__ gp,
    float* __restrict__ gq, float* __restrict__ gc, int N, int chunk) {
    int lane = threadIdx.x & 63;
    int wid = (blockIdx.x * blockDim.x + threadIdx.x) >> 6;
    int n0 = wid * chunk;
    int n1 = min(n0 + chunk, N);
    int curg = -1;
    float acct = 0.f;             // per-lane T partial
    float accq = 0.f, accc = 0.f; // lane-0 S/count partials
    for (int node = n0; node < n1; ++node) {
        int g = batch[node];
        if (g != curg) {
            if (curg >= 0) {
                float t = acct;
#pragma unroll
                for (int off = 32; off; off >>= 1) t += __shfl_xor(t, off);
                if (lane == 0) {
                    atomicAdd(&gp[curg], t);
                    atomicAdd(&gq[curg], accq);
                    atomicAdd(&gc[curg], accc);
                }
            }
            curg = g;
            acct = 0.f;
            accq = 0.f;
            accc = 0.f;
        }
        if (lane == 0) {
            accq += q[node];
            accc += 1.f;
        }
        int beg = row_ptr[node], end = row_ptr[node + 1];
        for (int jj = beg + lane; jj < end; jj += 64) {
            int2 e = csr[jj];
            acct += __int_as_float(e.y) * p[e.x];
        }
    }
    if (curg >= 0) {
        float t = acct;
#pragma unroll
        for (int off = 32; off; off >>= 1) t += __shfl_xor(t, off);
        if (lane == 0) {
            atomicAdd(&gp[curg], t);
            atomicAdd(&gq[curg], accq);
            atomicAdd(&gc[curg], accc);
        }
    }
}

// ---- kernel 7: epilogue ----------------------------------------------------
__global__ void final_kernel(const float* __restrict__ gp,
                             const float* __restrict__ gq,
                             const float* __restrict__ gc,
                             const float* __restrict__ C,
                             float* __restrict__ out) {
    int g = threadIdx.x;  // 128 threads
    float c = fmaxf(gc[g], 1.0f);
    out[g] = (gp[g] + gq[g]) / c + *C;
}

extern "C" void kernel_launch(void* const* d_in, const int* in_sizes, int n_in,
                              void* d_out, int out_size, void* d_ws,
                              size_t ws_size, hipStream_t stream) {
    const float* x      = (const float*)d_in[0];   // [N,64]
    const int*   ei     = (const int*)d_in[1];     // [2,E]
    const float* ew     = (const float*)d_in[2];   // [E]
    const int*   batch  = (const int*)d_in[3];     // [N] sorted
    const float* w1rel  = (const float*)d_in[4];
    const float* b1rel  = (const float*)d_in[5];
    const float* w1root = (const float*)d_in[6];
    const float* w2rel  = (const float*)d_in[7];
    const float* b2rel  = (const float*)d_in[8];
    const float* w2root = (const float*)d_in[9];
    const float* wlin   = (const float*)d_in[10];
    const float* blin   = (const float*)d_in[11];
    float* out = (float*)d_out;

    // ---- workspace layout (≈22.9 MB) ----
    char* wsb = (char*)d_ws;
    int2* csr = (int2*)wsb;                                        // 8 MB
    unsigned short* aggr = (unsigned short*)(wsb + (size_t)N_EDGES * 8);  // 12.8 MB
    unsigned short* whirel  = aggr + (size_t)N_NODES * 64;
    unsigned short* wlorel  = whirel + 4096;
    unsigned short* whiroot = wlorel + 4096;
    unsigned short* wloroot = whiroot + 4096;
    float* p  = (float*)(wloroot + 4096);
    float* q  = p + N_NODES;
    float* u  = q + N_NODES;
    float* v  = u + 64;
    float* gp = v + 64;
    float* gq = gp + NGRAPHS;
    float* gc = gq + NGRAPHS;
    float* C  = gc + NGRAPHS;
    int* deg      = (int*)(C + 1);
    int* row_ptr  = deg + N_NODES;
    int* cursor   = row_ptr + (N_NODES + 1);
    int* blocksum = cursor + N_NODES;  // 128

    hipMemsetAsync(deg, 0, N_NODES * sizeof(int), stream);
    hipMemsetAsync(gp, 0, (3 * NGRAPHS + 1) * sizeof(float), stream);

    prep_kernel<<<1, 256, 0, stream>>>(w1rel, w1root, w2rel, w2root, wlin,
                                       b2rel, blin, whirel, wlorel, whiroot,
                                       wloroot, u, v, C);

    int eblocks = (N_EDGES + 255) / 256;
    hist_kernel<<<eblocks, 256, 0, stream>>>(ei, deg, N_EDGES);
    scan_phaseA<<<SCAN_NB, 1024, 0, stream>>>(deg, blocksum, N_NODES);
    scan_phaseB<<<1, 128, 0, stream>>>(blocksum, SCAN_NB);
    scan_phaseC<<<SCAN_NB, 1024, 0, stream>>>(deg, blocksum, row_ptr, cursor,
                                              N_NODES);
    fill_kernel<<<eblocks, 256, 0, stream>>>(ei, ew, cursor, csr, N_EDGES);

    {
        int blocks = 2048;  // 8192 waves, low VGPR -> deep latency hiding
        int waves = blocks * 4;
        int chunk = (N_NODES + waves - 1) / waves;  // 13
        gather_kernel<<<blocks, 256, 0, stream>>>(x, row_ptr, csr, aggr,
                                                  N_NODES, chunk);
    }
    {
        int tiles = N_NODES / 16;                  // 6250
        int blocks = (tiles + 3) / 4;              // 1563
        dense_kernel<<<blocks, 256, 0, stream>>>(aggr, x, whirel, wlorel,
                                                 whiroot, wloroot, b1rel, u, v,
                                                 p, q, N_NODES);
    }
    {
        int blocks = 512;  // 2048 waves
        int waves = blocks * 4;
        int chunk = (N_NODES + waves - 1) / waves;  // 49
        pool_kernel<<<blocks, 256, 0, stream>>>(row_ptr, csr, p, q, batch, gp,
                                                gq, gc, N_NODES, chunk);
    }
    final_kernel<<<1, NGRAPHS, 0, stream>>>(gp, gq, gc, C, out);
}